// Round 6
// baseline (247.546 us; speedup 1.0000x reference)
//
#include <hip/hip_runtime.h>

typedef __bf16 bf16;
typedef __bf16 bf16x8 __attribute__((ext_vector_type(8)));
typedef float  f32x4  __attribute__((ext_vector_type(4)));
typedef float  f32x16 __attribute__((ext_vector_type(16)));
typedef unsigned u32x4 __attribute__((ext_vector_type(4)));

#define MFMA16(a,b,c) __builtin_amdgcn_mfma_f32_16x16x32_bf16((a),(b),(c),0,0,0)
#define MFMA32(a,b,c) __builtin_amdgcn_mfma_f32_32x32x16_bf16((a),(b),(c),0,0,0)

// ---- constants: B=4, S=2048, D=512, H=8, hd=64 ----
#define BATCH 4
#define SEQ   2048
#define DIM   512
#define NH    8
#define HD    64
// 0.125 * log2(e): folded into q at projection time so exp(x*0.125) == exp2(q_scaled . k)
#define QSCALE 0.18033688f

// swizzled LDS tile: [row][64] bf16, 8-elem units XOR'd by (row&7) -> even bank spread
__device__ __forceinline__ bf16x8 ldsfrag(const bf16* t, int row, int kc, int quad){
    int unit = ((kc << 2) + quad) ^ (row & 7);
    return *(const bf16x8*)(t + row * 64 + unit * 8);
}
// same swizzle, unit given directly (for 32x32 fragment reads)
__device__ __forceinline__ bf16x8 ldsfrag32(const bf16* t, int row, int unit){
    return *(const bf16x8*)(t + row * 64 + ((unit ^ (row & 7)) << 3));
}

__device__ __forceinline__ void stage64x64(const bf16* src, long rowStride, bf16* dst, int tid){
#pragma unroll
    for (int rnd = 0; rnd < 2; ++rnd){
        int sid = tid + rnd * 256;          // 512 segs of 8 bf16
        int row = sid >> 3, s = sid & 7;
        bf16x8 val = *(const bf16x8*)(src + (long)row * rowStride + s * 8);
        *(bf16x8*)(dst + row * 64 + ((s ^ (row & 7)) << 3)) = val;
    }
}

// pack two f32 -> one u32 of 2 bf16 (compiler emits v_cvt_pk_bf16_f32)
__device__ __forceinline__ unsigned packbf(float lo, float hi){
    unsigned short lb = __builtin_bit_cast(unsigned short, (bf16)lo);
    unsigned short hb = __builtin_bit_cast(unsigned short, (bf16)hi);
    return (unsigned)lb | ((unsigned)hb << 16);
}

// ---------------- kernel 0a: x f32 -> bf16 ----------------
__global__ __launch_bounds__(256) void cvt_x(const float* __restrict__ x, bf16* __restrict__ xb){
    int i = blockIdx.x * 256 + threadIdx.x;
    float4 f = ((const float4*)x)[i];
    bf16* o = xb + 4 * (long)i;
    o[0] = (bf16)f.x; o[1] = (bf16)f.y; o[2] = (bf16)f.z; o[3] = (bf16)f.w;
}

// ---------------- kernel 0b: W f32 [k][n] -> WT bf16 [n][k] ----------------
__global__ __launch_bounds__(256) void cvt_wt(const float* __restrict__ Wq, const float* __restrict__ Wk,
                                              const float* __restrict__ Wv, const float* __restrict__ Wo,
                                              bf16* __restrict__ WTb){
    int z = blockIdx.z;
    const float* W = (z == 0) ? Wq : (z == 1) ? Wk : (z == 2) ? Wv : Wo;
    bf16* WT = WTb + (long)z * DIM * DIM;
    __shared__ float lt[32 * 33];
    int t = threadIdx.x, r0 = t >> 5, c = t & 31;
    int k0 = blockIdx.x * 32, n0 = blockIdx.y * 32;
#pragma unroll
    for (int i = 0; i < 4; ++i){
        int row = r0 + i * 8;
        lt[row * 33 + c] = W[(long)(k0 + row) * DIM + n0 + c];
    }
    __syncthreads();
#pragma unroll
    for (int i = 0; i < 4; ++i){
        int nr = r0 + i * 8;
        WT[(long)(n0 + nr) * DIM + k0 + c] = (bf16)lt[c * 33 + nr];
    }
}

// ---------------- kernel 1: QKV projection GEMM ----------------
__global__ __launch_bounds__(256) void gemm_qkv(const bf16* __restrict__ X, const bf16* __restrict__ WTb,
                                                const float* __restrict__ bq, const float* __restrict__ bk,
                                                const float* __restrict__ bv, bf16* __restrict__ outb){
    __shared__ __align__(16) bf16 lA[128 * 64];
    __shared__ __align__(16) bf16 lB[128 * 64];
    int z = blockIdx.z;
    const bf16* WT = WTb + (long)z * DIM * DIM;
    const float* bias = (z == 0) ? bq : (z == 1) ? bk : bv;
    float qs = (z == 0) ? QSCALE : 1.0f;
    bf16* out = outb + (long)z * BATCH * SEQ * DIM;
    int tid = threadIdx.x, lane = tid & 63, w = tid >> 6;
    int wm = w >> 1, wn = w & 1;
    int m0 = blockIdx.y * 128, n0 = blockIdx.x * 128;
    int r16 = lane & 15, quad = lane >> 4;
    f32x4 zz = {0.f, 0.f, 0.f, 0.f};
    f32x4 acc[4][4];
#pragma unroll
    for (int a = 0; a < 4; ++a)
#pragma unroll
        for (int b2 = 0; b2 < 4; ++b2) acc[a][b2] = zz;

    for (int k0 = 0; k0 < DIM; k0 += 64){
        __syncthreads();
#pragma unroll
        for (int rnd = 0; rnd < 4; ++rnd){
            int sid = tid + rnd * 256;
            int row = sid >> 3, s = sid & 7;
            *(bf16x8*)(lA + row * 64 + ((s ^ (row & 7)) << 3)) =
                *(const bf16x8*)(X + (long)(m0 + row) * DIM + k0 + s * 8);
            *(bf16x8*)(lB + row * 64 + ((s ^ (row & 7)) << 3)) =
                *(const bf16x8*)(WT + (long)(n0 + row) * DIM + k0 + s * 8);
        }
        __syncthreads();
#pragma unroll
        for (int kc = 0; kc < 2; ++kc){
            bf16x8 aF[4], bF[4];
#pragma unroll
            for (int i = 0; i < 4; ++i){
                aF[i] = ldsfrag(lA, wm * 64 + i * 16 + r16, kc, quad);
                bF[i] = ldsfrag(lB, wn * 64 + i * 16 + r16, kc, quad);
            }
#pragma unroll
            for (int rb = 0; rb < 4; ++rb)
#pragma unroll
                for (int nb = 0; nb < 4; ++nb)
                    acc[rb][nb] = MFMA16(aF[rb], bF[nb], acc[rb][nb]);
        }
    }
#pragma unroll
    for (int nb = 0; nb < 4; ++nb){
        int col = n0 + wn * 64 + nb * 16 + r16;
        float bv_ = bias[col];
        int hh = col >> 6, d = col & 63;
#pragma unroll
        for (int rb = 0; rb < 4; ++rb)
#pragma unroll
            for (int r = 0; r < 4; ++r){
                int row = m0 + wm * 64 + rb * 16 + quad * 4 + r;
                int bb = row >> 11, s = row & 2047;
                out[((long)(bb * NH + hh) * SEQ + s) * HD + d] = (bf16)((acc[rb][nb][r] + bv_) * qs);
            }
    }
}

// ---------------- kernel 1.5: v [B,H,S,hd] -> vT [B,H,hd,S] ----------------
__global__ __launch_bounds__(256) void vtrans(const bf16* __restrict__ v, bf16* __restrict__ vT){
    __shared__ bf16 lt[64 * 72];
    int tid = threadIdx.x;
    int s0 = blockIdx.x * 64;
    int bh = blockIdx.z * NH + blockIdx.y;
#pragma unroll
    for (int rnd = 0; rnd < 2; ++rnd){
        int sid = tid + rnd * 256;
        int row = sid >> 3, sg = sid & 7;
        *(bf16x8*)(lt + row * 72 + sg * 8) =
            *(const bf16x8*)(v + ((long)bh * SEQ + s0 + row) * HD + sg * 8);
    }
    __syncthreads();
#pragma unroll
    for (int rnd = 0; rnd < 2; ++rnd){
        int sid = tid + rnd * 256;
        int d = sid >> 3, sg = sid & 7;
        bf16x8 o;
#pragma unroll
        for (int j = 0; j < 8; ++j) o[j] = lt[(sg * 8 + j) * 72 + d];
        *(bf16x8*)(vT + ((long)bh * HD + d) * SEQ + s0 + sg * 8) = o;
    }
}

// ---------------- kernel 2: flash attention, 32x32 MFMA, P in registers ----------------
// Swapped QK^T: D = MFMA32(K_frag, Q_frag) -> D[key][q], col=lane&31 = q. Each lane
// owns ONE q-row: lsum is a scalar (+ one shfl_xor(32) at the end), and the PV
// A-fragment is built in-register via cvt_pk + shfl_xor(32) half-exchange + cndmask.
// No P LDS buffer, no lgkmcnt drain. LDS = lQ 16KB + lK 8KB + lV 8KB = 32KB.
__global__ __launch_bounds__(256) void attn_flash(const bf16* __restrict__ q, const bf16* __restrict__ k,
                                                  const bf16* __restrict__ vT, bf16* __restrict__ ctx,
                                                  float* __restrict__ llv_g){
    __shared__ __align__(16) bf16 lQ[128 * 64];
    __shared__ __align__(16) bf16 lK[64 * 64];
    __shared__ __align__(16) bf16 lV[64 * 64];
    int tid = threadIdx.x, lane = tid & 63, w = tid >> 6;
    int lin = blockIdx.x + (blockIdx.y << 4) + (blockIdx.z << 7);    // 0..511
    int task = ((lin & 7) << 6) + (lin >> 3);                        // bijective XCD swizzle
    int qt = task & 15, h = (task >> 4) & 7, b = task >> 7;
    int bh = b * NH + h;
    int q0 = qt * 128;
    int row32 = lane & 31, half = lane >> 5;

    // stage Q 128x64 (swizzled)
    {
        const bf16* src = q + ((long)bh * SEQ + q0) * HD;
#pragma unroll
        for (int rnd = 0; rnd < 4; ++rnd){
            int sid = tid + rnd * 256;
            int row = sid >> 3, s = sid & 7;
            *(bf16x8*)(lQ + row * 64 + ((s ^ (row & 7)) << 3)) =
                *(const bf16x8*)(src + (long)row * HD + s * 8);
        }
    }
    __syncthreads();
    bf16x8 qF[4];
#pragma unroll
    for (int s = 0; s < 4; ++s) qF[s] = ldsfrag32(lQ, w * 32 + row32, 2 * s + half);

    f32x16 ctxacc[2];
#pragma unroll
    for (int i = 0; i < 16; ++i){ ctxacc[0][i] = 0.f; ctxacc[1][i] = 0.f; }
    float lsum = 0.f;

    // staging registers (T14 split)
    int r0_ = tid >> 3, s_ = tid & 7;
    const bf16* kbase = k + (long)bh * SEQ * HD;
    const bf16* vbase = vT + (long)bh * HD * SEQ;
    bf16x8 kr0, kr1, vr0, vr1;

    auto LOADREGS = [&](int j0){
        kr0 = *(const bf16x8*)(kbase + (long)(j0 + r0_) * HD + s_ * 8);
        kr1 = *(const bf16x8*)(kbase + (long)(j0 + r0_ + 32) * HD + s_ * 8);
        vr0 = *(const bf16x8*)(vbase + (long)r0_ * SEQ + j0 + s_ * 8);
        vr1 = *(const bf16x8*)(vbase + (long)(r0_ + 32) * SEQ + j0 + s_ * 8);
    };
    auto WRITELDS = [&](){
        int u = (s_ ^ (r0_ & 7)) << 3;
        *(bf16x8*)(lK + r0_ * 64 + u) = kr0;
        *(bf16x8*)(lK + (r0_ + 32) * 64 + u) = kr1;
        *(bf16x8*)(lV + r0_ * 64 + u) = vr0;
        *(bf16x8*)(lV + (r0_ + 32) * 64 + u) = vr1;
    };
    auto COMPUTE = [&](){
        __builtin_amdgcn_s_setprio(1);
#pragma unroll
        for (int kb = 0; kb < 2; ++kb){
            // swapped QK^T: D[key][q], col = lane&31 = q
            f32x16 sacc;
#pragma unroll
            for (int i = 0; i < 16; ++i) sacc[i] = 0.f;
#pragma unroll
            for (int s = 0; s < 4; ++s)
                sacc = MFMA32(ldsfrag32(lK, kb * 32 + row32, 2 * s + half), qF[s], sacc);
            // p[reg]: key = kb*32 + (reg&3) + 8*(reg>>2) + 4*half (this lane's q-row)
            float p[16];
#pragma unroll
            for (int reg = 0; reg < 16; ++reg){
                p[reg] = __builtin_amdgcn_exp2f(sacc[reg]);
                lsum += p[reg];
            }
            // pack pairs: Wp[b][j] = bf16x2 of keys (a=2j,2j+1), b index, own half
            unsigned Wp[4][2];
#pragma unroll
            for (int b2 = 0; b2 < 4; ++b2)
#pragma unroll
                for (int j = 0; j < 2; ++j)
                    Wp[b2][j] = packbf(p[4 * b2 + 2 * j], p[4 * b2 + 2 * j + 1]);
            // build PV A-fragments per k-slice and multiply
#pragma unroll
            for (int K = 0; K < 2; ++K){
                unsigned X0 = Wp[2 * K + 1][0], X1 = Wp[2 * K + 1][1];
                unsigned Y0 = Wp[2 * K][0],     Y1 = Wp[2 * K][1];
                unsigned X0p = (unsigned)__shfl_xor((int)X0, 32, 64);
                unsigned X1p = (unsigned)__shfl_xor((int)X1, 32, 64);
                unsigned Y0p = (unsigned)__shfl_xor((int)Y0, 32, 64);
                unsigned Y1p = (unsigned)__shfl_xor((int)Y1, 32, 64);
                u32x4 wv;
                wv[0] = half ? X0p : Y0;     // elems 0-1: keys base+8h+{0,1}
                wv[1] = half ? X1p : Y1;     // elems 2-3
                wv[2] = half ? X0  : Y0p;    // elems 4-5
                wv[3] = half ? X1  : Y1p;    // elems 6-7
                bf16x8 pa = __builtin_bit_cast(bf16x8, wv);
                int ks = 2 * kb + K;
#pragma unroll
                for (int db = 0; db < 2; ++db)
                    ctxacc[db] = MFMA32(pa, ldsfrag32(lV, db * 32 + row32, 2 * ks + half), ctxacc[db]);
            }
        }
        __builtin_amdgcn_s_setprio(0);
    };

    LOADREGS(0);
    WRITELDS();
    __syncthreads();
    for (int j0 = 0; j0 < SEQ - 64; j0 += 64){
        LOADREGS(j0 + 64);        // in flight across the whole compute phase
        COMPUTE();
        __syncthreads();          // all waves done reading lK/lV
        WRITELDS();               // compiler inserts the vmcnt wait here
        __syncthreads();          // writes visible
    }
    COMPUTE();

    // total row-sum for this lane's q-row: other half holds the complementary keys
    lsum += __shfl_xor(lsum, 32, 64);
    float rv = 1.0f / lsum;
    // redistribute rinv to C/D reg layout (lane qr holds q-row qr's sum)
    float rinv[16];
#pragma unroll
    for (int reg = 0; reg < 16; ++reg){
        int qr = (reg & 3) + 8 * (reg >> 2) + 4 * half;
        rinv[reg] = __shfl(rv, qr, 64);
    }
#pragma unroll
    for (int db = 0; db < 2; ++db)
#pragma unroll
        for (int reg = 0; reg < 16; ++reg){
            int qr = (reg & 3) + 8 * (reg >> 2) + 4 * half;
            long srow = q0 + w * 32 + qr;
            ctx[((long)b * SEQ + srow) * DIM + h * HD + db * 32 + row32] =
                (bf16)(ctxacc[db][reg] * rinv[reg]);
        }
    if (half == 0)
        llv_g[(long)bh * SEQ + q0 + w * 32 + row32] = -__log2f(lsum) - 3.0f;
}

// ---------------- kernel 3: avg_attn (LDS-staged mini-GEMM over heads, T14 prefetch) ----------------
__global__ __launch_bounds__(256) void attn_avg(const bf16* __restrict__ q, const bf16* __restrict__ k,
                                                const float* __restrict__ llv_g, float* __restrict__ avg){
    __shared__ __align__(16) bf16 lQ[64 * 64];
    __shared__ __align__(16) bf16 lK[64 * 64];
    __shared__ __align__(16) float lsOut[4][16 * 65];   // per-wave padded transpose buffer
    int lin  = blockIdx.x + (blockIdx.y << 5) + (blockIdx.z << 10);   // 0..4095
    int task = ((lin & 7) << 9) + (lin >> 3);                         // bijective XCD swizzle
    int qt = task & 31;
    int jt = (task >> 5) & 31;
    int b  = task >> 10;
    int tid = threadIdx.x, lane = tid & 63, w = tid >> 6;
    int r16 = lane & 15, quad = lane >> 4;
    int qbase = qt * 64;
    int j0 = jt * 64;

    // T14 split staging: issue next head's loads during current head's compute
    int r0_ = tid >> 3, s_ = tid & 7;
    int u_ = (s_ ^ (r0_ & 7)) << 3;
    bf16x8 qr0, qr1, kr0, kr1;
    auto LOADA = [&](int hh){
        long hA = (long)b * NH + hh;
        const bf16* qh = q + (hA * SEQ + qbase) * HD;
        const bf16* kh = k + (hA * SEQ + j0) * HD;
        qr0 = *(const bf16x8*)(qh + (long)r0_ * HD + s_ * 8);
        qr1 = *(const bf16x8*)(qh + (long)(r0_ + 32) * HD + s_ * 8);
        kr0 = *(const bf16x8*)(kh + (long)r0_ * HD + s_ * 8);
        kr1 = *(const bf16x8*)(kh + (long)(r0_ + 32) * HD + s_ * 8);
    };
    auto WRITEA = [&](){
        *(bf16x8*)(lQ + r0_ * 64 + u_) = qr0;
        *(bf16x8*)(lQ + (r0_ + 32) * 64 + u_) = qr1;
        *(bf16x8*)(lK + r0_ * 64 + u_) = kr0;
        *(bf16x8*)(lK + (r0_ + 32) * 64 + u_) = kr1;
    };

    f32x4 psum[4];
#pragma unroll
    for (int cb = 0; cb < 4; ++cb) psum[cb] = (f32x4){0.f, 0.f, 0.f, 0.f};

    LOADA(0);
    WRITEA();
    __syncthreads();
#pragma unroll 1
    for (int hh = 0; hh < NH; ++hh){
        if (hh < NH - 1) LOADA(hh + 1);          // global loads in flight over compute
        f32x4 llv = *(const f32x4*)(llv_g + ((long)b * NH + hh) * SEQ + qbase + w * 16 + quad * 4);
        bf16x8 aF0 = ldsfrag(lQ, w * 16 + r16, 0, quad);
        bf16x8 aF1 = ldsfrag(lQ, w * 16 + r16, 1, quad);
#pragma unroll
        for (int cb = 0; cb < 4; ++cb){
            f32x4 sa = MFMA16(aF0, ldsfrag(lK, cb * 16 + r16, 0, quad), llv);
            sa = MFMA16(aF1, ldsfrag(lK, cb * 16 + r16, 1, quad), sa);
#pragma unroll
            for (int r = 0; r < 4; ++r)
                psum[cb][r] += __builtin_amdgcn_exp2f(sa[r]);
        }
        __syncthreads();                          // all reads of lQ/lK done
        if (hh < NH - 1){
            WRITEA();                             // vmcnt wait inserted by compiler
            __syncthreads();                      // writes visible
        }
    }

    // wave-private transpose: psum -> lsOut[w], then line-complete f32x4 stores
#pragma unroll
    for (int cb = 0; cb < 4; ++cb)
#pragma unroll
        for (int r = 0; r < 4; ++r)
            lsOut[w][(quad * 4 + r) * 65 + cb * 16 + r16] = psum[cb][r];
#pragma unroll
    for (int i = 0; i < 4; ++i){
        int row  = ((i >> 1) << 3) + (lane >> 3);        // strip-local row 0..15
        int col4 = ((i & 1) << 5) + ((lane & 7) << 2);   // f32 col: 0..63
        f32x4 v = *(const f32x4*)(&lsOut[w][row * 65 + col4]);
        __builtin_nontemporal_store(v,
            (f32x4*)&avg[((long)b * SEQ + qbase + w * 16 + row) * SEQ + j0 + col4]);
    }
}

// ---------------- kernel 4: output projection ----------------
__global__ __launch_bounds__(256) void gemm_out(const bf16* __restrict__ CTX, const bf16* __restrict__ WT,
                                                const float* __restrict__ bo, float* __restrict__ out){
    __shared__ __align__(16) bf16 lA[128 * 64];
    __shared__ __align__(16) bf16 lB[128 * 64];
    int tid = threadIdx.x, lane = tid & 63, w = tid >> 6;
    int wm = w >> 1, wn = w & 1;
    int m0 = blockIdx.y * 128, n0 = blockIdx.x * 128;
    int r16 = lane & 15, quad = lane >> 4;
    f32x4 zz = {0.f, 0.f, 0.f, 0.f};
    f32x4 acc[4][4];
#pragma unroll
    for (int a = 0; a < 4; ++a)
#pragma unroll
        for (int b2 = 0; b2 < 4; ++b2) acc[a][b2] = zz;

    for (int k0 = 0; k0 < DIM; k0 += 64){
        __syncthreads();
#pragma unroll
        for (int rnd = 0; rnd < 4; ++rnd){
            int sid = tid + rnd * 256;
            int row = sid >> 3, s = sid & 7;
            *(bf16x8*)(lA + row * 64 + ((s ^ (row & 7)) << 3)) =
                *(const bf16x8*)(CTX + (long)(m0 + row) * DIM + k0 + s * 8);
            *(bf16x8*)(lB + row * 64 + ((s ^ (row & 7)) << 3)) =
                *(const bf16x8*)(WT + (long)(n0 + row) * DIM + k0 + s * 8);
        }
        __syncthreads();
#pragma unroll
        for (int kc = 0; kc < 2; ++kc){
            bf16x8 aF[4], bF[4];
#pragma unroll
            for (int i = 0; i < 4; ++i){
                aF[i] = ldsfrag(lA, wm * 64 + i * 16 + r16, kc, quad);
                bF[i] = ldsfrag(lB, wn * 64 + i * 16 + r16, kc, quad);
            }
#pragma unroll
            for (int rb2 = 0; rb2 < 4; ++rb2)
#pragma unroll
                for (int nb = 0; nb < 4; ++nb)
                    acc[rb2][nb] = MFMA16(aF[rb2], bF[nb], acc[rb2][nb]);
        }
    }
#pragma unroll
    for (int nb = 0; nb < 4; ++nb){
        int col = n0 + wn * 64 + nb * 16 + r16;
        float bv_ = bo[col];
#pragma unroll
        for (int rb2 = 0; rb2 < 4; ++rb2)
#pragma unroll
            for (int r = 0; r < 4; ++r){
                int row = m0 + wm * 64 + rb2 * 16 + quad * 4 + r;
                out[(long)row * DIM + col] = acc[rb2][nb][r] + bv_;
            }
    }
}

extern "C" void kernel_launch(void* const* d_in, const int* in_sizes, int n_in,
                              void* d_out, int out_size, void* d_ws, size_t ws_size,
                              hipStream_t stream) {
    const float* x  = (const float*)d_in[0];
    const float* Wq = (const float*)d_in[1];
    const float* bq = (const float*)d_in[2];
    const float* Wk = (const float*)d_in[3];
    const float* bk = (const float*)d_in[4];
    const float* Wv = (const float*)d_in[5];
    const float* bv = (const float*)d_in[6];
    const float* Wo = (const float*)d_in[7];
    const float* bo = (const float*)d_in[8];
    float* out = (float*)d_out;

    char* ws = (char*)d_ws;
    // ws layout (bytes): xb 8.0MB | WT 2MB | q,k,v 3x8MB | vT 8MB | ctx 8MB | llv 256KB
    bf16*  xb   = (bf16*)(ws);
    bf16*  WT   = (bf16*)(ws + 8388608);
    bf16*  qb   = (bf16*)(ws + 10485760);
    bf16*  kb   = qb + (long)BATCH * SEQ * DIM;
    bf16*  vb   = kb + (long)BATCH * SEQ * DIM;
    bf16*  vT   = (bf16*)(ws + 35651584);
    bf16*  ctx  = (bf16*)(ws + 44040192);
    float* llv  = (float*)(ws + 52428800);

    cvt_x    <<<4096, 256, 0, stream>>>(x, xb);
    cvt_wt   <<<dim3(16, 16, 4), 256, 0, stream>>>(Wq, Wk, Wv, Wo, WT);
    gemm_qkv <<<dim3(4, 64, 3), 256, 0, stream>>>(xb, WT, bq, bk, bv, qb);
    vtrans   <<<dim3(32, 8, 4), 256, 0, stream>>>(vb, vT);
    attn_flash<<<dim3(16, 8, 4), 256, 0, stream>>>(qb, kb, vT, ctx, llv);
    attn_avg <<<dim3(32, 32, 4), 256, 0, stream>>>(qb, kb, llv, out + (long)BATCH * SEQ * DIM);
    gemm_out <<<dim3(4, 64), 256, 0, stream>>>(ctx, WT + 3L * DIM * DIM, bo, out);
}

// Round 7
// 240.082 us; speedup vs baseline: 1.0311x; 1.0311x over previous
//
#include <hip/hip_runtime.h>

typedef __bf16 bf16;
typedef __bf16 bf16x8 __attribute__((ext_vector_type(8)));
typedef float  f32x4  __attribute__((ext_vector_type(4)));
typedef float  f32x16 __attribute__((ext_vector_type(16)));
typedef unsigned u32x4 __attribute__((ext_vector_type(4)));

#define MFMA16(a,b,c) __builtin_amdgcn_mfma_f32_16x16x32_bf16((a),(b),(c),0,0,0)
#define MFMA32(a,b,c) __builtin_amdgcn_mfma_f32_32x32x16_bf16((a),(b),(c),0,0,0)

// ---- constants: B=4, S=2048, D=512, H=8, hd=64 ----
#define BATCH 4
#define SEQ   2048
#define DIM   512
#define NH    8
#define HD    64
// 0.125 * log2(e): folded into q at projection time so exp(x*0.125) == exp2(q_scaled . k)
#define QSCALE 0.18033688f

// swizzled LDS tile: [row][64] bf16, 8-elem units XOR'd by (row&7) -> even bank spread
__device__ __forceinline__ bf16x8 ldsfrag(const bf16* t, int row, int kc, int quad){
    int unit = ((kc << 2) + quad) ^ (row & 7);
    return *(const bf16x8*)(t + row * 64 + unit * 8);
}
// same swizzle, unit given directly (for 32x32 fragment reads)
__device__ __forceinline__ bf16x8 ldsfrag32(const bf16* t, int row, int unit){
    return *(const bf16x8*)(t + row * 64 + ((unit ^ (row & 7)) << 3));
}

__device__ __forceinline__ void stage64x64(const bf16* src, long rowStride, bf16* dst, int tid){
#pragma unroll
    for (int rnd = 0; rnd < 2; ++rnd){
        int sid = tid + rnd * 256;          // 512 segs of 8 bf16
        int row = sid >> 3, s = sid & 7;
        bf16x8 val = *(const bf16x8*)(src + (long)row * rowStride + s * 8);
        *(bf16x8*)(dst + row * 64 + ((s ^ (row & 7)) << 3)) = val;
    }
}

// pack two f32 -> one u32 of 2 bf16 (compiler emits v_cvt_pk_bf16_f32)
__device__ __forceinline__ unsigned packbf(float lo, float hi){
    unsigned short lb = __builtin_bit_cast(unsigned short, (bf16)lo);
    unsigned short hb = __builtin_bit_cast(unsigned short, (bf16)hi);
    return (unsigned)lb | ((unsigned)hb << 16);
}

// ---------------- kernel 0a: x f32 -> bf16 ----------------
__global__ __launch_bounds__(256) void cvt_x(const float* __restrict__ x, bf16* __restrict__ xb){
    int i = blockIdx.x * 256 + threadIdx.x;
    float4 f = ((const float4*)x)[i];
    bf16* o = xb + 4 * (long)i;
    o[0] = (bf16)f.x; o[1] = (bf16)f.y; o[2] = (bf16)f.z; o[3] = (bf16)f.w;
}

// ---------------- kernel 0b: W f32 [k][n] -> WT bf16 [n][k] ----------------
__global__ __launch_bounds__(256) void cvt_wt(const float* __restrict__ Wq, const float* __restrict__ Wk,
                                              const float* __restrict__ Wv, const float* __restrict__ Wo,
                                              bf16* __restrict__ WTb){
    int z = blockIdx.z;
    const float* W = (z == 0) ? Wq : (z == 1) ? Wk : (z == 2) ? Wv : Wo;
    bf16* WT = WTb + (long)z * DIM * DIM;
    __shared__ float lt[32 * 33];
    int t = threadIdx.x, r0 = t >> 5, c = t & 31;
    int k0 = blockIdx.x * 32, n0 = blockIdx.y * 32;
#pragma unroll
    for (int i = 0; i < 4; ++i){
        int row = r0 + i * 8;
        lt[row * 33 + c] = W[(long)(k0 + row) * DIM + n0 + c];
    }
    __syncthreads();
#pragma unroll
    for (int i = 0; i < 4; ++i){
        int nr = r0 + i * 8;
        WT[(long)(n0 + nr) * DIM + k0 + c] = (bf16)lt[c * 33 + nr];
    }
}

// ---------------- kernel 1: QKV projection GEMM ----------------
__global__ __launch_bounds__(256) void gemm_qkv(const bf16* __restrict__ X, const bf16* __restrict__ WTb,
                                                const float* __restrict__ bq, const float* __restrict__ bk,
                                                const float* __restrict__ bv, bf16* __restrict__ outb){
    __shared__ __align__(16) bf16 lA[128 * 64];
    __shared__ __align__(16) bf16 lB[128 * 64];
    int z = blockIdx.z;
    const bf16* WT = WTb + (long)z * DIM * DIM;
    const float* bias = (z == 0) ? bq : (z == 1) ? bk : bv;
    float qs = (z == 0) ? QSCALE : 1.0f;
    bf16* out = outb + (long)z * BATCH * SEQ * DIM;
    int tid = threadIdx.x, lane = tid & 63, w = tid >> 6;
    int wm = w >> 1, wn = w & 1;
    int m0 = blockIdx.y * 128, n0 = blockIdx.x * 128;
    int r16 = lane & 15, quad = lane >> 4;
    f32x4 zz = {0.f, 0.f, 0.f, 0.f};
    f32x4 acc[4][4];
#pragma unroll
    for (int a = 0; a < 4; ++a)
#pragma unroll
        for (int b2 = 0; b2 < 4; ++b2) acc[a][b2] = zz;

    for (int k0 = 0; k0 < DIM; k0 += 64){
        __syncthreads();
#pragma unroll
        for (int rnd = 0; rnd < 4; ++rnd){
            int sid = tid + rnd * 256;
            int row = sid >> 3, s = sid & 7;
            *(bf16x8*)(lA + row * 64 + ((s ^ (row & 7)) << 3)) =
                *(const bf16x8*)(X + (long)(m0 + row) * DIM + k0 + s * 8);
            *(bf16x8*)(lB + row * 64 + ((s ^ (row & 7)) << 3)) =
                *(const bf16x8*)(WT + (long)(n0 + row) * DIM + k0 + s * 8);
        }
        __syncthreads();
#pragma unroll
        for (int kc = 0; kc < 2; ++kc){
            bf16x8 aF[4], bF[4];
#pragma unroll
            for (int i = 0; i < 4; ++i){
                aF[i] = ldsfrag(lA, wm * 64 + i * 16 + r16, kc, quad);
                bF[i] = ldsfrag(lB, wn * 64 + i * 16 + r16, kc, quad);
            }
#pragma unroll
            for (int rb = 0; rb < 4; ++rb)
#pragma unroll
                for (int nb = 0; nb < 4; ++nb)
                    acc[rb][nb] = MFMA16(aF[rb], bF[nb], acc[rb][nb]);
        }
    }
#pragma unroll
    for (int nb = 0; nb < 4; ++nb){
        int col = n0 + wn * 64 + nb * 16 + r16;
        float bv_ = bias[col];
        int hh = col >> 6, d = col & 63;
#pragma unroll
        for (int rb = 0; rb < 4; ++rb)
#pragma unroll
            for (int r = 0; r < 4; ++r){
                int row = m0 + wm * 64 + rb * 16 + quad * 4 + r;
                int bb = row >> 11, s = row & 2047;
                out[((long)(bb * NH + hh) * SEQ + s) * HD + d] = (bf16)((acc[rb][nb][r] + bv_) * qs);
            }
    }
}

// ---------------- kernel 1.5: v [B,H,S,hd] -> vT [B,H,hd,S] ----------------
__global__ __launch_bounds__(256) void vtrans(const bf16* __restrict__ v, bf16* __restrict__ vT){
    __shared__ bf16 lt[64 * 72];
    int tid = threadIdx.x;
    int s0 = blockIdx.x * 64;
    int bh = blockIdx.z * NH + blockIdx.y;
#pragma unroll
    for (int rnd = 0; rnd < 2; ++rnd){
        int sid = tid + rnd * 256;
        int row = sid >> 3, sg = sid & 7;
        *(bf16x8*)(lt + row * 72 + sg * 8) =
            *(const bf16x8*)(v + ((long)bh * SEQ + s0 + row) * HD + sg * 8);
    }
    __syncthreads();
#pragma unroll
    for (int rnd = 0; rnd < 2; ++rnd){
        int sid = tid + rnd * 256;
        int d = sid >> 3, sg = sid & 7;
        bf16x8 o;
#pragma unroll
        for (int j = 0; j < 8; ++j) o[j] = lt[(sg * 8 + j) * 72 + d];
        *(bf16x8*)(vT + ((long)bh * HD + d) * SEQ + s0 + sg * 8) = o;
    }
}

// ---------------- kernel 2: flash attention, 32x32 MFMA, j-split wave groups ----------------
// 512 threads = 2 groups x 4 waves. Group g handles keys [g*1024, g*1024+1024) with its
// own double-buffered K/V LDS pair -> ONE barrier per j-iteration (ping-pong ordering:
// the end-of-iter barrier both publishes writes of buf^1 and guarantees all reads of
// buf^1's previous contents finished one iteration ago). 16 iters/group instead of 32.
// Epilogue: group 1 exchanges f32 ctxacc+lsum via LDS; group 0 combines + stores.
// Waves/CU doubles to 16; barrier crossings drop 65 -> 18.
__global__ __launch_bounds__(512) void attn_flash(const bf16* __restrict__ q, const bf16* __restrict__ k,
                                                  const bf16* __restrict__ vT, bf16* __restrict__ ctx,
                                                  float* __restrict__ llv_g){
    __shared__ __align__(16) bf16 lQ[128 * 64];
    __shared__ __align__(16) bf16 lKV[2][2][8192];   // [group][buf][ K:0..4095 | V:4096..8191 ]
    int tid = threadIdx.x, lane = tid & 63, w = tid >> 6;
    int g = w >> 2, wq = w & 3;                      // group, wave-in-group
    int t256 = tid & 255;
    int lin = blockIdx.x + (blockIdx.y << 4) + (blockIdx.z << 7);    // 0..511
    int task = ((lin & 7) << 6) + (lin >> 3);                        // bijective XCD swizzle
    int qt = task & 15, h = (task >> 4) & 7, b = task >> 7;
    int bh = b * NH + h;
    int q0 = qt * 128;
    int row32 = lane & 31, half = lane >> 5;

    // staging roles within the group (256 threads cover 64 rows x 8 segs)
    int r0_ = t256 >> 3, s_ = t256 & 7;
    const bf16* kbase = k + ((long)bh * SEQ + g * (SEQ / 2)) * HD;
    const bf16* vbase = vT + (long)bh * HD * SEQ + g * (SEQ / 2);
    bf16x8 kr0, kr1, vr0, vr1;

    auto LOADREGS = [&](int jt){
        int j0 = jt * 64;
        kr0 = *(const bf16x8*)(kbase + (long)(j0 + r0_) * HD + s_ * 8);
        kr1 = *(const bf16x8*)(kbase + (long)(j0 + r0_ + 32) * HD + s_ * 8);
        vr0 = *(const bf16x8*)(vbase + (long)r0_ * SEQ + j0 + s_ * 8);
        vr1 = *(const bf16x8*)(vbase + (long)(r0_ + 32) * SEQ + j0 + s_ * 8);
    };
    auto WRITELDS = [&](int buf){
        bf16* lK = lKV[g][buf];
        bf16* lV = lK + 4096;
        int u = (s_ ^ (r0_ & 7)) << 3;
        *(bf16x8*)(lK + r0_ * 64 + u) = kr0;
        *(bf16x8*)(lK + (r0_ + 32) * 64 + u) = kr1;
        *(bf16x8*)(lV + r0_ * 64 + u) = vr0;
        *(bf16x8*)(lV + (r0_ + 32) * 64 + u) = vr1;
    };

    LOADREGS(0);                       // first K/V tile in flight under Q staging
    {
        const bf16* src = q + ((long)bh * SEQ + q0) * HD;
#pragma unroll
        for (int rnd = 0; rnd < 2; ++rnd){
            int sid = tid + rnd * 512;
            int row = sid >> 3, s = sid & 7;
            *(bf16x8*)(lQ + row * 64 + ((s ^ (row & 7)) << 3)) =
                *(const bf16x8*)(src + (long)row * HD + s * 8);
        }
    }
    __syncthreads();
    bf16x8 qF[4];
#pragma unroll
    for (int s = 0; s < 4; ++s) qF[s] = ldsfrag32(lQ, wq * 32 + row32, 2 * s + half);

    f32x16 ctxacc[2];
#pragma unroll
    for (int i = 0; i < 16; ++i){ ctxacc[0][i] = 0.f; ctxacc[1][i] = 0.f; }
    float lsum = 0.f;

    auto COMPUTE = [&](int buf){
        const bf16* lK = lKV[g][buf];
        const bf16* lV = lK + 4096;
        __builtin_amdgcn_s_setprio(1);
#pragma unroll
        for (int kb = 0; kb < 2; ++kb){
            // swapped QK^T: D[key][q], col = lane&31 = q
            f32x16 sacc;
#pragma unroll
            for (int i = 0; i < 16; ++i) sacc[i] = 0.f;
#pragma unroll
            for (int s = 0; s < 4; ++s)
                sacc = MFMA32(ldsfrag32(lK, kb * 32 + row32, 2 * s + half), qF[s], sacc);
            float p[16];
#pragma unroll
            for (int reg = 0; reg < 16; ++reg){
                p[reg] = __builtin_amdgcn_exp2f(sacc[reg]);
                lsum += p[reg];
            }
            unsigned Wp[4][2];
#pragma unroll
            for (int b2 = 0; b2 < 4; ++b2)
#pragma unroll
                for (int j = 0; j < 2; ++j)
                    Wp[b2][j] = packbf(p[4 * b2 + 2 * j], p[4 * b2 + 2 * j + 1]);
#pragma unroll
            for (int K = 0; K < 2; ++K){
                unsigned X0 = Wp[2 * K + 1][0], X1 = Wp[2 * K + 1][1];
                unsigned Y0 = Wp[2 * K][0],     Y1 = Wp[2 * K][1];
                unsigned X0p = (unsigned)__shfl_xor((int)X0, 32, 64);
                unsigned X1p = (unsigned)__shfl_xor((int)X1, 32, 64);
                unsigned Y0p = (unsigned)__shfl_xor((int)Y0, 32, 64);
                unsigned Y1p = (unsigned)__shfl_xor((int)Y1, 32, 64);
                u32x4 wv;
                wv[0] = half ? X0p : Y0;
                wv[1] = half ? X1p : Y1;
                wv[2] = half ? X0  : Y0p;
                wv[3] = half ? X1  : Y1p;
                bf16x8 pa = __builtin_bit_cast(bf16x8, wv);
                int ks = 2 * kb + K;
#pragma unroll
                for (int db = 0; db < 2; ++db)
                    ctxacc[db] = MFMA32(pa, ldsfrag32(lV, db * 32 + row32, 2 * ks + half), ctxacc[db]);
            }
        }
        __builtin_amdgcn_s_setprio(0);
    };

    WRITELDS(0);
    __syncthreads();
#pragma unroll 1
    for (int t = 0; t < 15; ++t){
        LOADREGS(t + 1);          // next tile's loads in flight over compute
        COMPUTE(t & 1);
        WRITELDS((t + 1) & 1);    // write the buffer NOT being read (vmcnt auto-wait)
        __syncthreads();          // publishes writes; also orders next-iter overwrite
    }
    COMPUTE(1);

    // ---- cross-group combine (exact f32) ----
    __syncthreads();                                 // all lKV reads done; safe to overlay
    float* xch = (float*)&lKV[0][0][0];              // 33.8 KB overlay (conflict-free stride 33)
    if (g == 1){
        float* dst = xch + ((wq << 6) + lane) * 33;
#pragma unroll
        for (int i = 0; i < 16; ++i){ dst[i] = ctxacc[0][i]; dst[16 + i] = ctxacc[1][i]; }
        dst[32] = lsum;
    }
    __syncthreads();
    if (g == 0){
        const float* src2 = xch + ((wq << 6) + lane) * 33;
#pragma unroll
        for (int i = 0; i < 16; ++i){ ctxacc[0][i] += src2[i]; ctxacc[1][i] += src2[16 + i]; }
        lsum += src2[32];
        lsum += __shfl_xor(lsum, 32, 64);            // other half's keys
        float rv = 1.0f / lsum;
        float rinv[16];
#pragma unroll
        for (int reg = 0; reg < 16; ++reg){
            int qr = (reg & 3) + 8 * (reg >> 2) + 4 * half;
            rinv[reg] = __shfl(rv, qr, 64);
        }
#pragma unroll
        for (int db = 0; db < 2; ++db)
#pragma unroll
            for (int reg = 0; reg < 16; ++reg){
                int qr = (reg & 3) + 8 * (reg >> 2) + 4 * half;
                long srow = q0 + wq * 32 + qr;
                ctx[((long)b * SEQ + srow) * DIM + h * HD + db * 32 + row32] =
                    (bf16)(ctxacc[db][reg] * rinv[reg]);
            }
        if (half == 0)
            llv_g[(long)bh * SEQ + q0 + wq * 32 + row32] = -__log2f(lsum) - 3.0f;
    }
}

// ---------------- kernel 3: avg_attn (LDS-staged mini-GEMM over heads, T14 prefetch) ----------------
__global__ __launch_bounds__(256) void attn_avg(const bf16* __restrict__ q, const bf16* __restrict__ k,
                                                const float* __restrict__ llv_g, float* __restrict__ avg){
    __shared__ __align__(16) bf16 lQ[64 * 64];
    __shared__ __align__(16) bf16 lK[64 * 64];
    __shared__ __align__(16) float lsOut[4][16 * 65];   // per-wave padded transpose buffer
    int lin  = blockIdx.x + (blockIdx.y << 5) + (blockIdx.z << 10);   // 0..4095
    int task = ((lin & 7) << 9) + (lin >> 3);                         // bijective XCD swizzle
    int qt = task & 31;
    int jt = (task >> 5) & 31;
    int b  = task >> 10;
    int tid = threadIdx.x, lane = tid & 63, w = tid >> 6;
    int r16 = lane & 15, quad = lane >> 4;
    int qbase = qt * 64;
    int j0 = jt * 64;

    // T14 split staging: issue next head's loads during current head's compute
    int r0_ = tid >> 3, s_ = tid & 7;
    int u_ = (s_ ^ (r0_ & 7)) << 3;
    bf16x8 qr0, qr1, kr0, kr1;
    auto LOADA = [&](int hh){
        long hA = (long)b * NH + hh;
        const bf16* qh = q + (hA * SEQ + qbase) * HD;
        const bf16* kh = k + (hA * SEQ + j0) * HD;
        qr0 = *(const bf16x8*)(qh + (long)r0_ * HD + s_ * 8);
        qr1 = *(const bf16x8*)(qh + (long)(r0_ + 32) * HD + s_ * 8);
        kr0 = *(const bf16x8*)(kh + (long)r0_ * HD + s_ * 8);
        kr1 = *(const bf16x8*)(kh + (long)(r0_ + 32) * HD + s_ * 8);
    };
    auto WRITEA = [&](){
        *(bf16x8*)(lQ + r0_ * 64 + u_) = qr0;
        *(bf16x8*)(lQ + (r0_ + 32) * 64 + u_) = qr1;
        *(bf16x8*)(lK + r0_ * 64 + u_) = kr0;
        *(bf16x8*)(lK + (r0_ + 32) * 64 + u_) = kr1;
    };

    f32x4 psum[4];
#pragma unroll
    for (int cb = 0; cb < 4; ++cb) psum[cb] = (f32x4){0.f, 0.f, 0.f, 0.f};

    LOADA(0);
    WRITEA();
    __syncthreads();
#pragma unroll 1
    for (int hh = 0; hh < NH; ++hh){
        if (hh < NH - 1) LOADA(hh + 1);          // global loads in flight over compute
        f32x4 llv = *(const f32x4*)(llv_g + ((long)b * NH + hh) * SEQ + qbase + w * 16 + quad * 4);
        bf16x8 aF0 = ldsfrag(lQ, w * 16 + r16, 0, quad);
        bf16x8 aF1 = ldsfrag(lQ, w * 16 + r16, 1, quad);
#pragma unroll
        for (int cb = 0; cb < 4; ++cb){
            f32x4 sa = MFMA16(aF0, ldsfrag(lK, cb * 16 + r16, 0, quad), llv);
            sa = MFMA16(aF1, ldsfrag(lK, cb * 16 + r16, 1, quad), sa);
#pragma unroll
            for (int r = 0; r < 4; ++r)
                psum[cb][r] += __builtin_amdgcn_exp2f(sa[r]);
        }
        __syncthreads();                          // all reads of lQ/lK done
        if (hh < NH - 1){
            WRITEA();                             // vmcnt wait inserted by compiler
            __syncthreads();                      // writes visible
        }
    }

    // wave-private transpose: psum -> lsOut[w], then line-complete f32x4 stores
#pragma unroll
    for (int cb = 0; cb < 4; ++cb)
#pragma unroll
        for (int r = 0; r < 4; ++r)
            lsOut[w][(quad * 4 + r) * 65 + cb * 16 + r16] = psum[cb][r];
#pragma unroll
    for (int i = 0; i < 4; ++i){
        int row  = ((i >> 1) << 3) + (lane >> 3);        // strip-local row 0..15
        int col4 = ((i & 1) << 5) + ((lane & 7) << 2);   // f32 col: 0..63
        f32x4 v = *(const f32x4*)(&lsOut[w][row * 65 + col4]);
        __builtin_nontemporal_store(v,
            (f32x4*)&avg[((long)b * SEQ + qbase + w * 16 + row) * SEQ + j0 + col4]);
    }
}

// ---------------- kernel 4: output projection ----------------
__global__ __launch_bounds__(256) void gemm_out(const bf16* __restrict__ CTX, const bf16* __restrict__ WT,
                                                const float* __restrict__ bo, float* __restrict__ out){
    __shared__ __align__(16) bf16 lA[128 * 64];
    __shared__ __align__(16) bf16 lB[128 * 64];
    int tid = threadIdx.x, lane = tid & 63, w = tid >> 6;
    int wm = w >> 1, wn = w & 1;
    int m0 = blockIdx.y * 128, n0 = blockIdx.x * 128;
    int r16 = lane & 15, quad = lane >> 4;
    f32x4 zz = {0.f, 0.f, 0.f, 0.f};
    f32x4 acc[4][4];
#pragma unroll
    for (int a = 0; a < 4; ++a)
#pragma unroll
        for (int b2 = 0; b2 < 4; ++b2) acc[a][b2] = zz;

    for (int k0 = 0; k0 < DIM; k0 += 64){
        __syncthreads();
#pragma unroll
        for (int rnd = 0; rnd < 4; ++rnd){
            int sid = tid + rnd * 256;
            int row = sid >> 3, s = sid & 7;
            *(bf16x8*)(lA + row * 64 + ((s ^ (row & 7)) << 3)) =
                *(const bf16x8*)(CTX + (long)(m0 + row) * DIM + k0 + s * 8);
            *(bf16x8*)(lB + row * 64 + ((s ^ (row & 7)) << 3)) =
                *(const bf16x8*)(WT + (long)(n0 + row) * DIM + k0 + s * 8);
        }
        __syncthreads();
#pragma unroll
        for (int kc = 0; kc < 2; ++kc){
            bf16x8 aF[4], bF[4];
#pragma unroll
            for (int i = 0; i < 4; ++i){
                aF[i] = ldsfrag(lA, wm * 64 + i * 16 + r16, kc, quad);
                bF[i] = ldsfrag(lB, wn * 64 + i * 16 + r16, kc, quad);
            }
#pragma unroll
            for (int rb2 = 0; rb2 < 4; ++rb2)
#pragma unroll
                for (int nb = 0; nb < 4; ++nb)
                    acc[rb2][nb] = MFMA16(aF[rb2], bF[nb], acc[rb2][nb]);
        }
    }
#pragma unroll
    for (int nb = 0; nb < 4; ++nb){
        int col = n0 + wn * 64 + nb * 16 + r16;
        float bv_ = bo[col];
#pragma unroll
        for (int rb2 = 0; rb2 < 4; ++rb2)
#pragma unroll
            for (int r = 0; r < 4; ++r){
                int row = m0 + wm * 64 + rb2 * 16 + quad * 4 + r;
                out[(long)row * DIM + col] = acc[rb2][nb][r] + bv_;
            }
    }
}

extern "C" void kernel_launch(void* const* d_in, const int* in_sizes, int n_in,
                              void* d_out, int out_size, void* d_ws, size_t ws_size,
                              hipStream_t stream) {
    const float* x  = (const float*)d_in[0];
    const float* Wq = (const float*)d_in[1];
    const float* bq = (const float*)d_in[2];
    const float* Wk = (const float*)d_in[3];
    const float* bk = (const float*)d_in[4];
    const float* Wv = (const float*)d_in[5];
    const float* bv = (const float*)d_in[6];
    const float* Wo = (const float*)d_in[7];
    const float* bo = (const float*)d_in[8];
    float* out = (float*)d_out;

    char* ws = (char*)d_ws;
    // ws layout (bytes): xb 8.0MB | WT 2MB | q,k,v 3x8MB | vT 8MB | ctx 8MB | llv 256KB
    bf16*  xb   = (bf16*)(ws);
    bf16*  WT   = (bf16*)(ws + 8388608);
    bf16*  qb   = (bf16*)(ws + 10485760);
    bf16*  kb   = qb + (long)BATCH * SEQ * DIM;
    bf16*  vb   = kb + (long)BATCH * SEQ * DIM;
    bf16*  vT   = (bf16*)(ws + 35651584);
    bf16*  ctx  = (bf16*)(ws + 44040192);
    float* llv  = (float*)(ws + 52428800);

    cvt_x    <<<4096, 256, 0, stream>>>(x, xb);
    cvt_wt   <<<dim3(16, 16, 4), 256, 0, stream>>>(Wq, Wk, Wv, Wo, WT);
    gemm_qkv <<<dim3(4, 64, 3), 256, 0, stream>>>(xb, WT, bq, bk, bv, qb);
    vtrans   <<<dim3(32, 8, 4), 256, 0, stream>>>(vb, vT);
    attn_flash<<<dim3(16, 8, 4), 512, 0, stream>>>(qb, kb, vT, ctx, llv);
    attn_avg <<<dim3(32, 32, 4), 256, 0, stream>>>(qb, kb, llv, out + (long)BATCH * SEQ * DIM);
    gemm_out <<<dim3(4, 64), 256, 0, stream>>>(ctx, WT + 3L * DIM * DIM, bo, out);
}

// Round 9
// 238.389 us; speedup vs baseline: 1.0384x; 1.0071x over previous
//
#include <hip/hip_runtime.h>

typedef __bf16 bf16;
typedef __bf16 bf16x8 __attribute__((ext_vector_type(8)));
typedef float  f32x4  __attribute__((ext_vector_type(4)));
typedef float  f32x16 __attribute__((ext_vector_type(16)));
typedef unsigned u32x4 __attribute__((ext_vector_type(4)));

#define MFMA16(a,b,c) __builtin_amdgcn_mfma_f32_16x16x32_bf16((a),(b),(c),0,0,0)
#define MFMA32(a,b,c) __builtin_amdgcn_mfma_f32_32x32x16_bf16((a),(b),(c),0,0,0)

// ---- constants: B=4, S=2048, D=512, H=8, hd=64 ----
#define BATCH 4
#define SEQ   2048
#define DIM   512
#define NH    8
#define HD    64
// 0.125 * log2(e): folded into q at projection time so exp(x*0.125) == exp2(q_scaled . k)
#define QSCALE 0.18033688f

// swizzled LDS tile: [row][64] bf16, 8-elem units XOR'd by (row&7) -> even bank spread
__device__ __forceinline__ bf16x8 ldsfrag(const bf16* t, int row, int kc, int quad){
    int unit = ((kc << 2) + quad) ^ (row & 7);
    return *(const bf16x8*)(t + row * 64 + unit * 8);
}
// same swizzle, unit given directly (for 32x32 fragment reads)
__device__ __forceinline__ bf16x8 ldsfrag32(const bf16* t, int row, int unit){
    return *(const bf16x8*)(t + row * 64 + ((unit ^ (row & 7)) << 3));
}

__device__ __forceinline__ void stage64x64(const bf16* src, long rowStride, bf16* dst, int tid){
#pragma unroll
    for (int rnd = 0; rnd < 2; ++rnd){
        int sid = tid + rnd * 256;          // 512 segs of 8 bf16
        int row = sid >> 3, s = sid & 7;
        bf16x8 val = *(const bf16x8*)(src + (long)row * rowStride + s * 8);
        *(bf16x8*)(dst + row * 64 + ((s ^ (row & 7)) << 3)) = val;
    }
}

// pack two f32 -> one u32 of 2 bf16 (compiler emits v_cvt_pk_bf16_f32)
__device__ __forceinline__ unsigned packbf(float lo, float hi){
    unsigned short lb = __builtin_bit_cast(unsigned short, (bf16)lo);
    unsigned short hb = __builtin_bit_cast(unsigned short, (bf16)hi);
    return (unsigned)lb | ((unsigned)hb << 16);
}

// ---------------- kernel 0a: x f32 -> bf16 ----------------
__global__ __launch_bounds__(256) void cvt_x(const float* __restrict__ x, bf16* __restrict__ xb){
    int i = blockIdx.x * 256 + threadIdx.x;
    float4 f = ((const float4*)x)[i];
    bf16* o = xb + 4 * (long)i;
    o[0] = (bf16)f.x; o[1] = (bf16)f.y; o[2] = (bf16)f.z; o[3] = (bf16)f.w;
}

// ---------------- kernel 0b: W f32 [k][n] -> WT bf16 [n][k] ----------------
__global__ __launch_bounds__(256) void cvt_wt(const float* __restrict__ Wq, const float* __restrict__ Wk,
                                              const float* __restrict__ Wv, const float* __restrict__ Wo,
                                              bf16* __restrict__ WTb){
    int z = blockIdx.z;
    const float* W = (z == 0) ? Wq : (z == 1) ? Wk : (z == 2) ? Wv : Wo;
    bf16* WT = WTb + (long)z * DIM * DIM;
    __shared__ float lt[32 * 33];
    int t = threadIdx.x, r0 = t >> 5, c = t & 31;
    int k0 = blockIdx.x * 32, n0 = blockIdx.y * 32;
#pragma unroll
    for (int i = 0; i < 4; ++i){
        int row = r0 + i * 8;
        lt[row * 33 + c] = W[(long)(k0 + row) * DIM + n0 + c];
    }
    __syncthreads();
#pragma unroll
    for (int i = 0; i < 4; ++i){
        int nr = r0 + i * 8;
        WT[(long)(n0 + nr) * DIM + k0 + c] = (bf16)lt[c * 33 + nr];
    }
}

// ---------------- kernel 1: QKV projection GEMM ----------------
__global__ __launch_bounds__(256) void gemm_qkv(const bf16* __restrict__ X, const bf16* __restrict__ WTb,
                                                const float* __restrict__ bq, const float* __restrict__ bk,
                                                const float* __restrict__ bv, bf16* __restrict__ outb){
    __shared__ __align__(16) bf16 lA[128 * 64];
    __shared__ __align__(16) bf16 lB[128 * 64];
    int z = blockIdx.z;
    const bf16* WT = WTb + (long)z * DIM * DIM;
    const float* bias = (z == 0) ? bq : (z == 1) ? bk : bv;
    float qs = (z == 0) ? QSCALE : 1.0f;
    bf16* out = outb + (long)z * BATCH * SEQ * DIM;
    int tid = threadIdx.x, lane = tid & 63, w = tid >> 6;
    int wm = w >> 1, wn = w & 1;
    int m0 = blockIdx.y * 128, n0 = blockIdx.x * 128;
    int r16 = lane & 15, quad = lane >> 4;
    f32x4 zz = {0.f, 0.f, 0.f, 0.f};
    f32x4 acc[4][4];
#pragma unroll
    for (int a = 0; a < 4; ++a)
#pragma unroll
        for (int b2 = 0; b2 < 4; ++b2) acc[a][b2] = zz;

    for (int k0 = 0; k0 < DIM; k0 += 64){
        __syncthreads();
#pragma unroll
        for (int rnd = 0; rnd < 4; ++rnd){
            int sid = tid + rnd * 256;
            int row = sid >> 3, s = sid & 7;
            *(bf16x8*)(lA + row * 64 + ((s ^ (row & 7)) << 3)) =
                *(const bf16x8*)(X + (long)(m0 + row) * DIM + k0 + s * 8);
            *(bf16x8*)(lB + row * 64 + ((s ^ (row & 7)) << 3)) =
                *(const bf16x8*)(WT + (long)(n0 + row) * DIM + k0 + s * 8);
        }
        __syncthreads();
#pragma unroll
        for (int kc = 0; kc < 2; ++kc){
            bf16x8 aF[4], bF[4];
#pragma unroll
            for (int i = 0; i < 4; ++i){
                aF[i] = ldsfrag(lA, wm * 64 + i * 16 + r16, kc, quad);
                bF[i] = ldsfrag(lB, wn * 64 + i * 16 + r16, kc, quad);
            }
#pragma unroll
            for (int rb = 0; rb < 4; ++rb)
#pragma unroll
                for (int nb = 0; nb < 4; ++nb)
                    acc[rb][nb] = MFMA16(aF[rb], bF[nb], acc[rb][nb]);
        }
    }
#pragma unroll
    for (int nb = 0; nb < 4; ++nb){
        int col = n0 + wn * 64 + nb * 16 + r16;
        float bv_ = bias[col];
        int hh = col >> 6, d = col & 63;
#pragma unroll
        for (int rb = 0; rb < 4; ++rb)
#pragma unroll
            for (int r = 0; r < 4; ++r){
                int row = m0 + wm * 64 + rb * 16 + quad * 4 + r;
                int bb = row >> 11, s = row & 2047;
                out[((long)(bb * NH + hh) * SEQ + s) * HD + d] = (bf16)((acc[rb][nb][r] + bv_) * qs);
            }
    }
}

// ---------------- kernel 1.5: v [B,H,S,hd] -> vT [B,H,hd,S] ----------------
__global__ __launch_bounds__(256) void vtrans(const bf16* __restrict__ v, bf16* __restrict__ vT){
    __shared__ bf16 lt[64 * 72];
    int tid = threadIdx.x;
    int s0 = blockIdx.x * 64;
    int bh = blockIdx.z * NH + blockIdx.y;
#pragma unroll
    for (int rnd = 0; rnd < 2; ++rnd){
        int sid = tid + rnd * 256;
        int row = sid >> 3, sg = sid & 7;
        *(bf16x8*)(lt + row * 72 + sg * 8) =
            *(const bf16x8*)(v + ((long)bh * SEQ + s0 + row) * HD + sg * 8);
    }
    __syncthreads();
#pragma unroll
    for (int rnd = 0; rnd < 2; ++rnd){
        int sid = tid + rnd * 256;
        int d = sid >> 3, sg = sid & 7;
        bf16x8 o;
#pragma unroll
        for (int j = 0; j < 8; ++j) o[j] = lt[(sg * 8 + j) * 72 + d];
        *(bf16x8*)(vT + ((long)bh * HD + d) * SEQ + s0 + sg * 8) = o;
    }
}

// ---------------- kernel 2: flash attention, 32x32 MFMA, j-split wave groups ----------------
// 512 threads = 2 groups x 4 waves, double-buffered K/V per group (one barrier/iter).
// Swapped QK^T -> P in registers. PA fragments via the VERIFIED shfl_xor+select path
// (R7; the permlane variant mispaired key halves — reverted). Row-sums via ones-MFMA:
// lsacc = MFMA32(pa, ones) accumulates sum_k P[q][k] directly in C/D layout -> no
// per-element VALU adds and no epilogue shuffle tree.
__global__ __launch_bounds__(512) void attn_flash(const bf16* __restrict__ q, const bf16* __restrict__ k,
                                                  const bf16* __restrict__ vT, bf16* __restrict__ ctx,
                                                  float* __restrict__ llv_g){
    __shared__ __align__(16) bf16 lQ[128 * 64];
    __shared__ __align__(16) bf16 lKV[2][2][8192];   // [group][buf][ K:0..4095 | V:4096..8191 ]
    int tid = threadIdx.x, lane = tid & 63, w = tid >> 6;
    int g = w >> 2, wq = w & 3;                      // group, wave-in-group
    int t256 = tid & 255;
    int lin = blockIdx.x + (blockIdx.y << 4) + (blockIdx.z << 7);    // 0..511
    int task = ((lin & 7) << 6) + (lin >> 3);                        // bijective XCD swizzle
    int qt = task & 15, h = (task >> 4) & 7, b = task >> 7;
    int bh = b * NH + h;
    int q0 = qt * 128;
    int row32 = lane & 31, half = lane >> 5;

    // staging roles within the group (256 threads cover 64 rows x 8 segs)
    int r0_ = t256 >> 3, s_ = t256 & 7;
    const bf16* kbase = k + ((long)bh * SEQ + g * (SEQ / 2)) * HD;
    const bf16* vbase = vT + (long)bh * HD * SEQ + g * (SEQ / 2);
    bf16x8 kr0, kr1, vr0, vr1;

    auto LOADREGS = [&](int jt){
        int j0 = jt * 64;
        kr0 = *(const bf16x8*)(kbase + (long)(j0 + r0_) * HD + s_ * 8);
        kr1 = *(const bf16x8*)(kbase + (long)(j0 + r0_ + 32) * HD + s_ * 8);
        vr0 = *(const bf16x8*)(vbase + (long)r0_ * SEQ + j0 + s_ * 8);
        vr1 = *(const bf16x8*)(vbase + (long)(r0_ + 32) * SEQ + j0 + s_ * 8);
    };
    auto WRITELDS = [&](int buf){
        bf16* lK = lKV[g][buf];
        bf16* lV = lK + 4096;
        int u = (s_ ^ (r0_ & 7)) << 3;
        *(bf16x8*)(lK + r0_ * 64 + u) = kr0;
        *(bf16x8*)(lK + (r0_ + 32) * 64 + u) = kr1;
        *(bf16x8*)(lV + r0_ * 64 + u) = vr0;
        *(bf16x8*)(lV + (r0_ + 32) * 64 + u) = vr1;
    };

    LOADREGS(0);                       // first K/V tile in flight under Q staging
    {
        const bf16* src = q + ((long)bh * SEQ + q0) * HD;
#pragma unroll
        for (int rnd = 0; rnd < 2; ++rnd){
            int sid = tid + rnd * 512;
            int row = sid >> 3, s = sid & 7;
            *(bf16x8*)(lQ + row * 64 + ((s ^ (row & 7)) << 3)) =
                *(const bf16x8*)(src + (long)row * HD + s * 8);
        }
    }
    __syncthreads();
    bf16x8 qF[4];
#pragma unroll
    for (int s = 0; s < 4; ++s) qF[s] = ldsfrag32(lQ, wq * 32 + row32, 2 * s + half);

    f32x16 ctxacc[2], lsacc;
#pragma unroll
    for (int i = 0; i < 16; ++i){ ctxacc[0][i] = 0.f; ctxacc[1][i] = 0.f; lsacc[i] = 0.f; }
    bf16x8 onesv;
#pragma unroll
    for (int i = 0; i < 8; ++i) onesv[i] = (bf16)1.0f;

    auto COMPUTE = [&](int buf){
        const bf16* lK = lKV[g][buf];
        const bf16* lV = lK + 4096;
        __builtin_amdgcn_s_setprio(1);
#pragma unroll
        for (int kb = 0; kb < 2; ++kb){
            // swapped QK^T: D[key][q], col = lane&31 = q
            f32x16 sacc;
#pragma unroll
            for (int i = 0; i < 16; ++i) sacc[i] = 0.f;
#pragma unroll
            for (int s = 0; s < 4; ++s)
                sacc = MFMA32(ldsfrag32(lK, kb * 32 + row32, 2 * s + half), qF[s], sacc);
            float p[16];
#pragma unroll
            for (int reg = 0; reg < 16; ++reg)
                p[reg] = __builtin_amdgcn_exp2f(sacc[reg]);
            unsigned Wp[4][2];
#pragma unroll
            for (int b2 = 0; b2 < 4; ++b2)
#pragma unroll
                for (int j = 0; j < 2; ++j)
                    Wp[b2][j] = packbf(p[4 * b2 + 2 * j], p[4 * b2 + 2 * j + 1]);
#pragma unroll
            for (int K = 0; K < 2; ++K){
                unsigned X0 = Wp[2 * K + 1][0], X1 = Wp[2 * K + 1][1];
                unsigned Y0 = Wp[2 * K][0],     Y1 = Wp[2 * K][1];
                unsigned X0p = (unsigned)__shfl_xor((int)X0, 32, 64);
                unsigned X1p = (unsigned)__shfl_xor((int)X1, 32, 64);
                unsigned Y0p = (unsigned)__shfl_xor((int)Y0, 32, 64);
                unsigned Y1p = (unsigned)__shfl_xor((int)Y1, 32, 64);
                u32x4 wv;
                wv[0] = half ? X0p : Y0;
                wv[1] = half ? X1p : Y1;
                wv[2] = half ? X0  : Y0p;
                wv[3] = half ? X1  : Y1p;
                bf16x8 pa = __builtin_bit_cast(bf16x8, wv);
                int ks = 2 * kb + K;
                lsacc = MFMA32(pa, onesv, lsacc);          // row-sums on the MFMA pipe
#pragma unroll
                for (int db = 0; db < 2; ++db)
                    ctxacc[db] = MFMA32(pa, ldsfrag32(lV, db * 32 + row32, 2 * ks + half), ctxacc[db]);
            }
        }
        __builtin_amdgcn_s_setprio(0);
    };

    WRITELDS(0);
    __syncthreads();
#pragma unroll 1
    for (int t = 0; t < 15; ++t){
        LOADREGS(t + 1);          // next tile's loads in flight over compute
        COMPUTE(t & 1);
        WRITELDS((t + 1) & 1);    // write the buffer NOT being read (vmcnt auto-wait)
        __syncthreads();          // publishes writes; also orders next-iter overwrite
    }
    COMPUTE(1);

    // ---- cross-group combine (exact f32; lsacc already in C/D layout) ----
    __syncthreads();                                 // all lKV reads done; safe to overlay
    float* xch = (float*)&lKV[0][0][0];              // 256 x 49 floats = 50.2 KB, odd stride conflict-free
    if (g == 1){
        float* dst = xch + ((wq << 6) + lane) * 49;
#pragma unroll
        for (int i = 0; i < 16; ++i){
            dst[i] = ctxacc[0][i]; dst[16 + i] = ctxacc[1][i]; dst[32 + i] = lsacc[i];
        }
    }
    __syncthreads();
    if (g == 0){
        const float* src2 = xch + ((wq << 6) + lane) * 49;
#pragma unroll
        for (int i = 0; i < 16; ++i){
            ctxacc[0][i] += src2[i]; ctxacc[1][i] += src2[16 + i]; lsacc[i] += src2[32 + i];
        }
        float rinv[16];
#pragma unroll
        for (int reg = 0; reg < 16; ++reg) rinv[reg] = 1.0f / lsacc[reg];
#pragma unroll
        for (int db = 0; db < 2; ++db)
#pragma unroll
            for (int reg = 0; reg < 16; ++reg){
                int qr = (reg & 3) + 8 * (reg >> 2) + 4 * half;
                long srow = q0 + wq * 32 + qr;
                ctx[((long)b * SEQ + srow) * DIM + h * HD + db * 32 + row32] =
                    (bf16)(ctxacc[db][reg] * rinv[reg]);
            }
        if (row32 == 0)                               // lanes 0 and 32 cover both halves
#pragma unroll
            for (int reg = 0; reg < 16; ++reg){
                int qr = (reg & 3) + 8 * (reg >> 2) + 4 * half;
                llv_g[(long)bh * SEQ + q0 + wq * 32 + qr] = -__log2f(lsacc[reg]) - 3.0f;
            }
    }
}

// ---------------- kernel 3: avg_attn (LDS-staged mini-GEMM over heads, T14 prefetch) ----------------
__global__ __launch_bounds__(256) void attn_avg(const bf16* __restrict__ q, const bf16* __restrict__ k,
                                                const float* __restrict__ llv_g, float* __restrict__ avg){
    __shared__ __align__(16) bf16 lQ[64 * 64];
    __shared__ __align__(16) bf16 lK[64 * 64];
    __shared__ __align__(16) float lsOut[4][16 * 65];   // per-wave padded transpose buffer
    int lin  = blockIdx.x + (blockIdx.y << 5) + (blockIdx.z << 10);   // 0..4095
    int task = ((lin & 7) << 9) + (lin >> 3);                         // bijective XCD swizzle
    int qt = task & 31;
    int jt = (task >> 5) & 31;
    int b  = task >> 10;
    int tid = threadIdx.x, lane = tid & 63, w = tid >> 6;
    int r16 = lane & 15, quad = lane >> 4;
    int qbase = qt * 64;
    int j0 = jt * 64;

    // T14 split staging: issue next head's loads during current head's compute
    int r0_ = tid >> 3, s_ = tid & 7;
    int u_ = (s_ ^ (r0_ & 7)) << 3;
    bf16x8 qr0, qr1, kr0, kr1;
    auto LOADA = [&](int hh){
        long hA = (long)b * NH + hh;
        const bf16* qh = q + (hA * SEQ + qbase) * HD;
        const bf16* kh = k + (hA * SEQ + j0) * HD;
        qr0 = *(const bf16x8*)(qh + (long)r0_ * HD + s_ * 8);
        qr1 = *(const bf16x8*)(qh + (long)(r0_ + 32) * HD + s_ * 8);
        kr0 = *(const bf16x8*)(kh + (long)r0_ * HD + s_ * 8);
        kr1 = *(const bf16x8*)(kh + (long)(r0_ + 32) * HD + s_ * 8);
    };
    auto WRITEA = [&](){
        *(bf16x8*)(lQ + r0_ * 64 + u_) = qr0;
        *(bf16x8*)(lQ + (r0_ + 32) * 64 + u_) = qr1;
        *(bf16x8*)(lK + r0_ * 64 + u_) = kr0;
        *(bf16x8*)(lK + (r0_ + 32) * 64 + u_) = kr1;
    };

    f32x4 psum[4];
#pragma unroll
    for (int cb = 0; cb < 4; ++cb) psum[cb] = (f32x4){0.f, 0.f, 0.f, 0.f};

    LOADA(0);
    WRITEA();
    __syncthreads();
#pragma unroll 1
    for (int hh = 0; hh < NH; ++hh){
        if (hh < NH - 1) LOADA(hh + 1);          // global loads in flight over compute
        f32x4 llv = *(const f32x4*)(llv_g + ((long)b * NH + hh) * SEQ + qbase + w * 16 + quad * 4);
        bf16x8 aF0 = ldsfrag(lQ, w * 16 + r16, 0, quad);
        bf16x8 aF1 = ldsfrag(lQ, w * 16 + r16, 1, quad);
#pragma unroll
        for (int cb = 0; cb < 4; ++cb){
            f32x4 sa = MFMA16(aF0, ldsfrag(lK, cb * 16 + r16, 0, quad), llv);
            sa = MFMA16(aF1, ldsfrag(lK, cb * 16 + r16, 1, quad), sa);
#pragma unroll
            for (int r = 0; r < 4; ++r)
                psum[cb][r] += __builtin_amdgcn_exp2f(sa[r]);
        }
        __syncthreads();                          // all reads of lQ/lK done
        if (hh < NH - 1){
            WRITEA();                             // vmcnt wait inserted by compiler
            __syncthreads();                      // writes visible
        }
    }

    // wave-private transpose: psum -> lsOut[w], then line-complete f32x4 stores
#pragma unroll
    for (int cb = 0; cb < 4; ++cb)
#pragma unroll
        for (int r = 0; r < 4; ++r)
            lsOut[w][(quad * 4 + r) * 65 + cb * 16 + r16] = psum[cb][r];
#pragma unroll
    for (int i = 0; i < 4; ++i){
        int row  = ((i >> 1) << 3) + (lane >> 3);        // strip-local row 0..15
        int col4 = ((i & 1) << 5) + ((lane & 7) << 2);   // f32 col: 0..63
        f32x4 v = *(const f32x4*)(&lsOut[w][row * 65 + col4]);
        __builtin_nontemporal_store(v,
            (f32x4*)&avg[((long)b * SEQ + qbase + w * 16 + row) * SEQ + j0 + col4]);
    }
}

// ---------------- kernel 4: output projection ----------------
__global__ __launch_bounds__(256) void gemm_out(const bf16* __restrict__ CTX, const bf16* __restrict__ WT,
                                                const float* __restrict__ bo, float* __restrict__ out){
    __shared__ __align__(16) bf16 lA[128 * 64];
    __shared__ __align__(16) bf16 lB[128 * 64];
    int tid = threadIdx.x, lane = tid & 63, w = tid >> 6;
    int wm = w >> 1, wn = w & 1;
    int m0 = blockIdx.y * 128, n0 = blockIdx.x * 128;
    int r16 = lane & 15, quad = lane >> 4;
    f32x4 zz = {0.f, 0.f, 0.f, 0.f};
    f32x4 acc[4][4];
#pragma unroll
    for (int a = 0; a < 4; ++a)
#pragma unroll
        for (int b2 = 0; b2 < 4; ++b2) acc[a][b2] = zz;

    for (int k0 = 0; k0 < DIM; k0 += 64){
        __syncthreads();
#pragma unroll
        for (int rnd = 0; rnd < 4; ++rnd){
            int sid = tid + rnd * 256;
            int row = sid >> 3, s = sid & 7;
            *(bf16x8*)(lA + row * 64 + ((s ^ (row & 7)) << 3)) =
                *(const bf16x8*)(CTX + (long)(m0 + row) * DIM + k0 + s * 8);
            *(bf16x8*)(lB + row * 64 + ((s ^ (row & 7)) << 3)) =
                *(const bf16x8*)(WT + (long)(n0 + row) * DIM + k0 + s * 8);
        }
        __syncthreads();
#pragma unroll
        for (int kc = 0; kc < 2; ++kc){
            bf16x8 aF[4], bF[4];
#pragma unroll
            for (int i = 0; i < 4; ++i){
                aF[i] = ldsfrag(lA, wm * 64 + i * 16 + r16, kc, quad);
                bF[i] = ldsfrag(lB, wn * 64 + i * 16 + r16, kc, quad);
            }
#pragma unroll
            for (int rb2 = 0; rb2 < 4; ++rb2)
#pragma unroll
                for (int nb = 0; nb < 4; ++nb)
                    acc[rb2][nb] = MFMA16(aF[rb2], bF[nb], acc[rb2][nb]);
        }
    }
#pragma unroll
    for (int nb = 0; nb < 4; ++nb){
        int col = n0 + wn * 64 + nb * 16 + r16;
        float bv_ = bo[col];
#pragma unroll
        for (int rb2 = 0; rb2 < 4; ++rb2)
#pragma unroll
            for (int r = 0; r < 4; ++r){
                int row = m0 + wm * 64 + rb2 * 16 + quad * 4 + r;
                out[(long)row * DIM + col] = acc[rb2][nb][r] + bv_;
            }
    }
}

extern "C" void kernel_launch(void* const* d_in, const int* in_sizes, int n_in,
                              void* d_out, int out_size, void* d_ws, size_t ws_size,
                              hipStream_t stream) {
    const float* x  = (const float*)d_in[0];
    const float* Wq = (const float*)d_in[1];
    const float* bq = (const float*)d_in[2];
    const float* Wk = (const float*)d_in[3];
    const float* bk = (const float*)d_in[4];
    const float* Wv = (const float*)d_in[5];
    const float* bv = (const float*)d_in[6];
    const float* Wo = (const float*)d_in[7];
    const float* bo = (const float*)d_in[8];
    float* out = (float*)d_out;

    char* ws = (char*)d_ws;
    // ws layout (bytes): xb 8.0MB | WT 2MB | q,k,v 3x8MB | vT 8MB | ctx 8MB | llv 256KB
    bf16*  xb   = (bf16*)(ws);
    bf16*  WT   = (bf16*)(ws + 8388608);
    bf16*  qb   = (bf16*)(ws + 10485760);
    bf16*  kb   = qb + (long)BATCH * SEQ * DIM;
    bf16*  vb   = kb + (long)BATCH * SEQ * DIM;
    bf16*  vT   = (bf16*)(ws + 35651584);
    bf16*  ctx  = (bf16*)(ws + 44040192);
    float* llv  = (float*)(ws + 52428800);

    cvt_x    <<<4096, 256, 0, stream>>>(x, xb);
    cvt_wt   <<<dim3(16, 16, 4), 256, 0, stream>>>(Wq, Wk, Wv, Wo, WT);
    gemm_qkv <<<dim3(4, 64, 3), 256, 0, stream>>>(xb, WT, bq, bk, bv, qb);
    vtrans   <<<dim3(32, 8, 4), 256, 0, stream>>>(vb, vT);
    attn_flash<<<dim3(16, 8, 4), 512, 0, stream>>>(qb, kb, vT, ctx, llv);
    attn_avg <<<dim3(32, 32, 4), 256, 0, stream>>>(qb, kb, llv, out + (long)BATCH * SEQ * DIM);
    gemm_out <<<dim3(4, 64), 256, 0, stream>>>(ctx, WT + 3L * DIM * DIM, bo, out);
}